// Round 5
// baseline (414.001 us; speedup 1.0000x reference)
//
#include <hip/hip_runtime.h>

// ---------------------------------------------------------------------------
// CrossAttention: out = mean_h softmax(softmax((x@Wq)/4 · K^T + v) * exp(cur))
// B=4096, IN=1024, H=16, E=256, N_EP=2048.
// Strategy: bf16 hi/lo split (3-pass MFMA) for fp32-class accuracy.
// k_attn v4: bh = depth-8 register pipeline; bl = LDS-DMA ring (depth 7 in
//            flight) with hand-counted vmcnt gates; fully unrolled K loop;
//            col-slice staggered per block to spread L2 traffic.
// ---------------------------------------------------------------------------

typedef __attribute__((ext_vector_type(8))) short bf16x8;
typedef __attribute__((ext_vector_type(4))) float f32x4;

typedef const __attribute__((address_space(1))) void* gcptr;
typedef __attribute__((address_space(3))) void* sptr;

__device__ __forceinline__ void gload16(const void* g, void* l) {
  __builtin_amdgcn_global_load_lds((gcptr)g, (sptr)l, 16, 0, 0);
}

// round-to-nearest-even fp32 -> bf16 (bit-level)
__device__ __forceinline__ unsigned short f2bf(float f) {
  unsigned int u = __float_as_uint(f);
  unsigned int r = (u + 0x7fffu + ((u >> 16) & 1u)) >> 16;
  return (unsigned short)r;
}
__device__ __forceinline__ float bf2f(unsigned short s) {
  return __uint_as_float(((unsigned int)s) << 16);
}

// ------------------------- elementwise split (x) ---------------------------
__global__ void k_split(const float* __restrict__ src,
                        unsigned short* __restrict__ hi,
                        unsigned short* __restrict__ lo, int n4) {
  int i = blockIdx.x * blockDim.x + threadIdx.x;
  if (i >= n4) return;
  float4 v = reinterpret_cast<const float4*>(src)[i];
  ushort4 h, l;
  h.x = f2bf(v.x); l.x = f2bf(v.x - bf2f(h.x));
  h.y = f2bf(v.y); l.y = f2bf(v.y - bf2f(h.y));
  h.z = f2bf(v.z); l.z = f2bf(v.z - bf2f(h.z));
  h.w = f2bf(v.w); l.w = f2bf(v.w - bf2f(h.w));
  reinterpret_cast<ushort4*>(hi)[i] = h;
  reinterpret_cast<ushort4*>(lo)[i] = l;
}

// ---- K prep: split + retile into MFMA-fragment order ----------------------
// K_t layout (per plane): [jg(128)][k0(8)][lane(64)][8 shorts]
//   lane lam <-> (row = jg*16 + (lam&15), col = k0*32 + (lam>>4)*8)
__global__ void k_prepk(const float* __restrict__ keys,
                        unsigned short* __restrict__ th,
                        unsigned short* __restrict__ tl) {
  int g = blockIdx.x * blockDim.x + threadIdx.x;  // 65536 chunks of 8 elems
  int jg = g >> 9, rem = g & 511;
  int k0 = rem >> 6, lam = rem & 63;
  int row = jg * 16 + (lam & 15);
  int col = k0 * 32 + (lam >> 4) * 8;
  const float* s = keys + (size_t)row * 256 + col;
  float4 v0 = *reinterpret_cast<const float4*>(s);
  float4 v1 = *reinterpret_cast<const float4*>(s + 4);
  ushort4 h0, h1, l0, l1;
  h0.x = f2bf(v0.x); l0.x = f2bf(v0.x - bf2f(h0.x));
  h0.y = f2bf(v0.y); l0.y = f2bf(v0.y - bf2f(h0.y));
  h0.z = f2bf(v0.z); l0.z = f2bf(v0.z - bf2f(h0.z));
  h0.w = f2bf(v0.w); l0.w = f2bf(v0.w - bf2f(h0.w));
  h1.x = f2bf(v1.x); l1.x = f2bf(v1.x - bf2f(h1.x));
  h1.y = f2bf(v1.y); l1.y = f2bf(v1.y - bf2f(h1.y));
  h1.z = f2bf(v1.z); l1.z = f2bf(v1.z - bf2f(h1.z));
  h1.w = f2bf(v1.w); l1.w = f2bf(v1.w - bf2f(h1.w));
  reinterpret_cast<ushort4*>(th + (size_t)g * 8)[0] = h0;
  reinterpret_cast<ushort4*>(th + (size_t)g * 8)[1] = h1;
  reinterpret_cast<ushort4*>(tl + (size_t)g * 8)[0] = l0;
  reinterpret_cast<ushort4*>(tl + (size_t)g * 8)[1] = l1;
}

// ---------------- transpose + split Wq [1024,4096] -> WqT [4096,1024] ------
__global__ void k_twq(const float* __restrict__ W,
                      unsigned short* __restrict__ th,
                      unsigned short* __restrict__ tl) {
  __shared__ float t[64][65];
  int tx = threadIdx.x & 63, ty = threadIdx.x >> 6;
  int c0 = blockIdx.x * 64, r0 = blockIdx.y * 64;
#pragma unroll
  for (int i = 0; i < 64; i += 4)
    t[ty + i][tx] = W[(size_t)(r0 + ty + i) * 4096 + (c0 + tx)] * 0.25f;
  __syncthreads();
#pragma unroll
  for (int i = 0; i < 64; i += 4) {
    float v = t[tx][ty + i];
    unsigned short h = f2bf(v);
    unsigned short l = f2bf(v - bf2f(h));
    size_t o = (size_t)(c0 + ty + i) * 1024 + (r0 + tx);
    th[o] = h; tl[o] = l;
  }
}

// ------------------- GEMM1: q = x @ WqT', both [.,K] row-major -------------
__global__ __launch_bounds__(256) void k_gemm1(
    const unsigned short* __restrict__ Ah, const unsigned short* __restrict__ Al,
    const unsigned short* __restrict__ Bh, const unsigned short* __restrict__ Bl,
    unsigned short* __restrict__ Qh, unsigned short* __restrict__ Ql) {
  __shared__ unsigned short As[2][128][32];
  __shared__ unsigned short Bs[2][128][32];
  const int tid = threadIdx.x;
  const int w = tid >> 6, l = tid & 63;
  const int lr = l & 15, lg = l >> 4;
  const int m0 = blockIdx.y * 128, n0 = blockIdx.x * 128;
  const int wr = (w >> 1) * 64, wc = (w & 1) * 64;
  const int srow = tid >> 2;
  const int skel = (tid & 3) * 8;
  f32x4 acc[4][4] = {};

  const size_t gaBase = (size_t)(m0 + srow) * 1024 + skel;
  const size_t gbBase = (size_t)(n0 + srow) * 1024 + skel;
  char* lA0 = (char*)&As[0][0][0] + w * 1024;
  char* lA1 = (char*)&As[1][0][0] + w * 1024;
  char* lB0 = (char*)&Bs[0][0][0] + w * 1024;
  char* lB1 = (char*)&Bs[1][0][0] + w * 1024;

  for (int k0 = 0; k0 < 1024; k0 += 32) {
    gload16(Ah + gaBase + k0,             lA0);
    gload16(Ah + gaBase + 64 * 1024 + k0, lA0 + 4096);
    gload16(Al + gaBase + k0,             lA1);
    gload16(Al + gaBase + 64 * 1024 + k0, lA1 + 4096);
    gload16(Bh + gbBase + k0,             lB0);
    gload16(Bh + gbBase + 64 * 1024 + k0, lB0 + 4096);
    gload16(Bl + gbBase + k0,             lB1);
    gload16(Bl + gbBase + 64 * 1024 + k0, lB1 + 4096);
    __syncthreads();
    bf16x8 ah[4], am[4], bh[4], bm[4];
#pragma unroll
    for (int i = 0; i < 4; ++i) {
      ah[i] = *reinterpret_cast<const bf16x8*>(&As[0][wr + i * 16 + lr][lg * 8]);
      am[i] = *reinterpret_cast<const bf16x8*>(&As[1][wr + i * 16 + lr][lg * 8]);
      bh[i] = *reinterpret_cast<const bf16x8*>(&Bs[0][wc + i * 16 + lr][lg * 8]);
      bm[i] = *reinterpret_cast<const bf16x8*>(&Bs[1][wc + i * 16 + lr][lg * 8]);
    }
#pragma unroll
    for (int i = 0; i < 4; ++i)
#pragma unroll
      for (int j = 0; j < 4; ++j) {
        acc[i][j] = __builtin_amdgcn_mfma_f32_16x16x32_bf16(ah[i], bh[j], acc[i][j], 0, 0, 0);
        acc[i][j] = __builtin_amdgcn_mfma_f32_16x16x32_bf16(am[i], bh[j], acc[i][j], 0, 0, 0);
        acc[i][j] = __builtin_amdgcn_mfma_f32_16x16x32_bf16(ah[i], bm[j], acc[i][j], 0, 0, 0);
      }
    __syncthreads();
  }
#pragma unroll
  for (int i = 0; i < 4; ++i)
#pragma unroll
    for (int j = 0; j < 4; ++j)
#pragma unroll
      for (int r = 0; r < 4; ++r) {
        int row = m0 + wr + i * 16 + lg * 4 + r;
        int col = n0 + wc + j * 16 + lr;
        float v = acc[i][j][r];
        unsigned short hh = f2bf(v);
        unsigned short ll = f2bf(v - bf2f(hh));
        size_t o = (size_t)row * 4096 + col;
        Qh[o] = hh; Ql[o] = ll;
      }
}

// ---- fused GEMM2 + double softmax + head-mean (v4) -------------------------
#define MFMA_BF16(a, b, c) __builtin_amdgcn_mfma_f32_16x16x32_bf16(a, b, c, 0, 0, 0)
#define GATE(N) asm volatile("s_waitcnt vmcnt(" #N ")" ::: "memory")

// One JSTEP: gate -> ds_read bl -> 6 MFMAs -> (opt) issue next pair
// SLOT: bh register slot + bl ring slot for THIS step (= J & 7)
// JT/KT/TSLOT: coordinates + slot of the pair issued 7 steps ahead
#define JST(J, SLOT, GN, ISSUE, JT, KT, TSLOT)                                   \
  GATE(GN);                                                                      \
  {                                                                              \
    bf16x8 blv = *reinterpret_cast<const bf16x8*>(ringS + (SLOT) * 512 + l8);    \
    acc[0][J] = MFMA_BF16(ah0, B##SLOT, acc[0][J]);                              \
    acc[1][J] = MFMA_BF16(ah1, B##SLOT, acc[1][J]);                              \
    acc[0][J] = MFMA_BF16(am0, B##SLOT, acc[0][J]);                              \
    acc[1][J] = MFMA_BF16(am1, B##SLOT, acc[1][J]);                              \
    acc[0][J] = MFMA_BF16(ah0, blv, acc[0][J]);                                  \
    acc[1][J] = MFMA_BF16(ah1, blv, acc[1][J]);                                  \
    if (ISSUE) {                                                                 \
      B##TSLOT = *reinterpret_cast<const bf16x8*>(kH + ((JT) * 8 + (KT)) * 512); \
      gload16(kL + ((JT) * 8 + (KT)) * 512, ringC + (TSLOT) * 1024);             \
    }                                                                            \
  }

#define BODY_HEAD(K)                                                   \
  ah0 = *reinterpret_cast<const bf16x8*>(SMs + ((K)) * 512 + l8);      \
  ah1 = *reinterpret_cast<const bf16x8*>(SMs + (8 + (K)) * 512 + l8);  \
  am0 = *reinterpret_cast<const bf16x8*>(SMs + (16 + (K)) * 512 + l8); \
  am1 = *reinterpret_cast<const bf16x8*>(SMs + (24 + (K)) * 512 + l8);

#define BODY(K)                  \
  BODY_HEAD(K)                   \
  JST(0, 0, 12, 1, 7, K, 7)      \
  JST(1, 1, 12, 1, 8, K, 0)      \
  JST(2, 2, 12, 1, 9, K, 1)      \
  JST(3, 3, 12, 1, 10, K, 2)     \
  JST(4, 4, 12, 1, 11, K, 3)     \
  JST(5, 5, 12, 1, 12, K, 4)     \
  JST(6, 6, 12, 1, 13, K, 5)     \
  JST(7, 7, 12, 1, 14, K, 6)     \
  JST(8, 0, 12, 1, 15, K, 7)     \
  JST(9, 1, 12, 1, 0, K + 1, 0)  \
  JST(10, 2, 12, 1, 1, K + 1, 1) \
  JST(11, 3, 12, 1, 2, K + 1, 2) \
  JST(12, 4, 12, 1, 3, K + 1, 3) \
  JST(13, 5, 12, 1, 4, K + 1, 4) \
  JST(14, 6, 12, 1, 5, K + 1, 5) \
  JST(15, 7, 12, 1, 6, K + 1, 6)

#define BODY7                   \
  BODY_HEAD(7)                  \
  JST(0, 0, 12, 1, 7, 7, 7)     \
  JST(1, 1, 12, 1, 8, 7, 0)     \
  JST(2, 2, 12, 1, 9, 7, 1)     \
  JST(3, 3, 12, 1, 10, 7, 2)    \
  JST(4, 4, 12, 1, 11, 7, 3)    \
  JST(5, 5, 12, 1, 12, 7, 4)    \
  JST(6, 6, 12, 1, 13, 7, 5)    \
  JST(7, 7, 12, 1, 14, 7, 6)    \
  JST(8, 0, 12, 1, 15, 7, 7)    \
  JST(9, 1, 12, 0, 0, 0, 0)     \
  JST(10, 2, 10, 0, 0, 0, 0)    \
  JST(11, 3, 8, 0, 0, 0, 0)     \
  JST(12, 4, 6, 0, 0, 0, 0)     \
  JST(13, 5, 4, 0, 0, 0, 0)     \
  JST(14, 6, 2, 0, 0, 0, 0)     \
  JST(15, 7, 0, 0, 0, 0, 0)

#define PROLOG(P)                                                  \
  B##P = *reinterpret_cast<const bf16x8*>(kH + (P) * 4096);        \
  gload16(kL + (P) * 4096, ringC + (P) * 1024);

// block: 512 thr (8 waves), 32 q2-rows, full N=2048; wave w owns the
// staggered col-slice ((w + bid) & 7)*256.
// LDS: [0,32KB) q-frags Asm; [32KB,96KB) bl ring 8 waves x 8 x 1KB;
//      [96KB, +1KB) red.
__global__ __launch_bounds__(512, 2) void k_attn(
    const unsigned short* __restrict__ Qh, const unsigned short* __restrict__ Ql,
    const unsigned short* __restrict__ KtH, const unsigned short* __restrict__ KtL,
    const float* __restrict__ values, const float* __restrict__ cur,
    float* __restrict__ out) {
  __shared__ short SMs[49664];  // 99328 B total
  const int tid = threadIdx.x;
  const int w = tid >> 6, l = tid & 63;
  const int lr = l & 15, lg = l >> 4;
  const int r0 = blockIdx.x * 32;          // q2 row base
  const int cs = (int)((w + blockIdx.x) & 7);  // staggered col-slice
  const int n0 = cs * 256;
  const int l8 = l * 8;

  // ---- stage q rows (hi+lo) into frag-major LDS; wave w does slots w*4..+3
#pragma unroll
  for (int qq = 0; qq < 4; ++qq) {
    const int s = w * 4 + qq;
    const int plane = s >> 4, mf = (s >> 3) & 1, k0s = s & 7;
    const unsigned short* src = plane ? Ql : Qh;
    const size_t ga = (size_t)(r0 + mf * 16 + lr) * 256 + k0s * 32 + lg * 8;
    gload16(src + ga, (char*)SMs + s * 1024);
  }
  asm volatile("s_waitcnt vmcnt(0)" ::: "memory");
  __syncthreads();

  const unsigned short* kH = KtH + (size_t)cs * 65536 + l8;
  const unsigned short* kL = KtL + (size_t)cs * 65536 + l8;
  short* ringS = SMs + 16384 + w * 4096;        // ds_read base (shorts)
  char* ringC = (char*)SMs + 32768 + w * 8192;  // DMA dest base (bytes)
  float (*red)[32] = (float(*)[32])(SMs + 49152);

  f32x4 acc[2][16] = {};
  bf16x8 B0, B1, B2, B3, B4, B5, B6, B7;
  bf16x8 ah0, ah1, am0, am1;

  // prologue: 7 pairs in flight (gj = 0..6)
  PROLOG(0) PROLOG(1) PROLOG(2) PROLOG(3) PROLOG(4) PROLOG(5) PROLOG(6)

  BODY(0) BODY(1) BODY(2) BODY(3) BODY(4) BODY(5) BODY(6) BODY7

  // logits = acc + values[n]
#pragma unroll
  for (int j = 0; j < 16; ++j) {
    float vv = values[n0 + j * 16 + lr];
#pragma unroll
    for (int mf = 0; mf < 2; ++mf)
#pragma unroll
      for (int r = 0; r < 4; ++r) acc[mf][j][r] += vv;
  }

  const int rb = lg * 4;
  // ---------------- first softmax: row max ----------------
  float M1[2][4];
#pragma unroll
  for (int mf = 0; mf < 2; ++mf)
#pragma unroll
    for (int r = 0; r < 4; ++r) {
      float m = acc[mf][0][r];
#pragma unroll
      for (int j = 1; j < 16; ++j) m = fmaxf(m, acc[mf][j][r]);
      m = fmaxf(m, __shfl_xor(m, 1));
      m = fmaxf(m, __shfl_xor(m, 2));
      m = fmaxf(m, __shfl_xor(m, 4));
      m = fmaxf(m, __shfl_xor(m, 8));
      M1[mf][r] = m;
    }
  if (lr == 0) {
#pragma unroll
    for (int mf = 0; mf < 2; ++mf)
#pragma unroll
      for (int r = 0; r < 4; ++r) red[w][mf * 16 + rb + r] = M1[mf][r];
  }
  __syncthreads();
#pragma unroll
  for (int mf = 0; mf < 2; ++mf)
#pragma unroll
    for (int r = 0; r < 4; ++r) {
      float m = red[0][mf * 16 + rb + r];
#pragma unroll
      for (int w2 = 1; w2 < 8; ++w2) m = fmaxf(m, red[w2][mf * 16 + rb + r]);
      M1[mf][r] = m;
    }
  __syncthreads();
  // ---------------- e1 = exp(l - M1), Z1 ----------------
  float Z1[2][4];
#pragma unroll
  for (int mf = 0; mf < 2; ++mf)
#pragma unroll
    for (int r = 0; r < 4; ++r) {
      float z = 0.f;
#pragma unroll
      for (int j = 0; j < 16; ++j) {
        float e = __expf(acc[mf][j][r] - M1[mf][r]);
        acc[mf][j][r] = e;
        z += e;
      }
      z += __shfl_xor(z, 1); z += __shfl_xor(z, 2);
      z += __shfl_xor(z, 4); z += __shfl_xor(z, 8);
      Z1[mf][r] = z;
    }
  if (lr == 0) {
#pragma unroll
    for (int mf = 0; mf < 2; ++mf)
#pragma unroll
      for (int r = 0; r < 4; ++r) red[w][mf * 16 + rb + r] = Z1[mf][r];
  }
  __syncthreads();
#pragma unroll
  for (int mf = 0; mf < 2; ++mf)
#pragma unroll
    for (int r = 0; r < 4; ++r) {
      float z = 0.f;
#pragma unroll
      for (int w2 = 0; w2 < 8; ++w2) z += red[w2][mf * 16 + rb + r];
      Z1[mf][r] = z;
    }
  __syncthreads();
  // ---------------- second softmax (max(logits2) = c/Z1 exactly) -----------
  const float c0 = __expf(cur[(r0 >> 4) + 0]);
  const float c1 = __expf(cur[(r0 >> 4) + 1]);
  float Z2[2][4];
#pragma unroll
  for (int mf = 0; mf < 2; ++mf)
#pragma unroll
    for (int r = 0; r < 4; ++r) {
      float s2 = (mf ? c1 : c0) / Z1[mf][r];
      float z = 0.f;
#pragma unroll
      for (int j = 0; j < 16; ++j) {
        float o = __expf(s2 * (acc[mf][j][r] - 1.0f));
        acc[mf][j][r] = o;
        z += o;
      }
      z += __shfl_xor(z, 1); z += __shfl_xor(z, 2);
      z += __shfl_xor(z, 4); z += __shfl_xor(z, 8);
      Z2[mf][r] = z;
    }
  if (lr == 0) {
#pragma unroll
    for (int mf = 0; mf < 2; ++mf)
#pragma unroll
      for (int r = 0; r < 4; ++r) red[w][mf * 16 + rb + r] = Z2[mf][r];
  }
  __syncthreads();
#pragma unroll
  for (int mf = 0; mf < 2; ++mf)
#pragma unroll
    for (int r = 0; r < 4; ++r) {
      float z = 0.f;
#pragma unroll
      for (int w2 = 0; w2 < 8; ++w2) z += red[w2][mf * 16 + rb + r];
      Z2[mf][r] = z;
    }
  // ---------------- head-mean + write ----------------
  float rz[2][4];
#pragma unroll
  for (int mf = 0; mf < 2; ++mf)
#pragma unroll
    for (int r = 0; r < 4; ++r) rz[mf][r] = 1.0f / (16.0f * Z2[mf][r]);
#pragma unroll
  for (int mf = 0; mf < 2; ++mf)
#pragma unroll
    for (int j = 0; j < 16; ++j) {
      float s = acc[mf][j][0] * rz[mf][0] + acc[mf][j][1] * rz[mf][1] +
                acc[mf][j][2] * rz[mf][2] + acc[mf][j][3] * rz[mf][3];
      s += __shfl_xor(s, 16);
      s += __shfl_xor(s, 32);
      if (l < 16)
        out[(size_t)((r0 >> 4) + mf) * 2048 + n0 + j * 16 + l] = s;
    }
}

// ---------------------------------------------------------------------------
extern "C" void kernel_launch(void* const* d_in, const int* in_sizes, int n_in,
                              void* d_out, int out_size, void* d_ws, size_t ws_size,
                              hipStream_t stream) {
  const float* x    = (const float*)d_in[0];
  const float* cur  = (const float*)d_in[1];
  const float* Wq   = (const float*)d_in[2];
  const float* keys = (const float*)d_in[3];
  const float* vals = (const float*)d_in[4];
  float* out = (float*)d_out;

  char* ws = (char*)d_ws;
  unsigned short* x_hi = (unsigned short*)ws;  ws += (size_t)4096 * 1024 * 2;
  unsigned short* x_lo = (unsigned short*)ws;  ws += (size_t)4096 * 1024 * 2;
  unsigned short* w_hi = (unsigned short*)ws;  ws += (size_t)4096 * 1024 * 2;
  unsigned short* w_lo = (unsigned short*)ws;  ws += (size_t)4096 * 1024 * 2;
  unsigned short* k_hi = (unsigned short*)ws;  ws += (size_t)2048 * 256 * 2;
  unsigned short* k_lo = (unsigned short*)ws;  ws += (size_t)2048 * 256 * 2;
  unsigned short* q_hi = (unsigned short*)ws;  ws += (size_t)4096 * 4096 * 2;
  unsigned short* q_lo = (unsigned short*)ws;

  k_split<<<4096, 256, 0, stream>>>(x, x_hi, x_lo, 4096 * 1024 / 4);
  k_prepk<<<256, 256, 0, stream>>>(keys, k_hi, k_lo);
  k_twq<<<dim3(64, 16), 256, 0, stream>>>(Wq, w_hi, w_lo);
  k_gemm1<<<dim3(32, 32), 256, 0, stream>>>(x_hi, x_lo, w_hi, w_lo, q_hi, q_lo);
  k_attn<<<2048, 512, 0, stream>>>(q_hi, q_lo, k_hi, k_lo, vals, cur, out);
}

// Round 6
// 377.177 us; speedup vs baseline: 1.0976x; 1.0976x over previous
//
#include <hip/hip_runtime.h>

// ---------------------------------------------------------------------------
// CrossAttention: out = mean_h softmax(softmax((x@Wq)/4 · K^T + v) * exp(cur))
// B=4096, IN=1024, H=16, E=256, N_EP=2048.
// Strategy: bf16 hi/lo split (3-pass MFMA) for fp32-class accuracy.
// k_attn v5: k-major K tiling -> monotone 1KB-stride load stream with
//            SGPR-base + 32-bit voffset addressing (no 64-bit addr VALU, no
//            spill); depth-4 named-register pipeline; setprio around MFMA.
// ---------------------------------------------------------------------------

typedef __attribute__((ext_vector_type(8))) short bf16x8;
typedef __attribute__((ext_vector_type(4))) float f32x4;

typedef const __attribute__((address_space(1))) void* gcptr;
typedef __attribute__((address_space(3))) void* sptr;

__device__ __forceinline__ void gload16(const void* g, void* l) {
  __builtin_amdgcn_global_load_lds((gcptr)g, (sptr)l, 16, 0, 0);
}

// round-to-nearest-even fp32 -> bf16 (bit-level)
__device__ __forceinline__ unsigned short f2bf(float f) {
  unsigned int u = __float_as_uint(f);
  unsigned int r = (u + 0x7fffu + ((u >> 16) & 1u)) >> 16;
  return (unsigned short)r;
}
__device__ __forceinline__ float bf2f(unsigned short s) {
  return __uint_as_float(((unsigned int)s) << 16);
}

// ------------------------- elementwise split (x) ---------------------------
__global__ void k_split(const float* __restrict__ src,
                        unsigned short* __restrict__ hi,
                        unsigned short* __restrict__ lo, int n4) {
  int i = blockIdx.x * blockDim.x + threadIdx.x;
  if (i >= n4) return;
  float4 v = reinterpret_cast<const float4*>(src)[i];
  ushort4 h, l;
  h.x = f2bf(v.x); l.x = f2bf(v.x - bf2f(h.x));
  h.y = f2bf(v.y); l.y = f2bf(v.y - bf2f(h.y));
  h.z = f2bf(v.z); l.z = f2bf(v.z - bf2f(h.z));
  h.w = f2bf(v.w); l.w = f2bf(v.w - bf2f(h.w));
  reinterpret_cast<ushort4*>(hi)[i] = h;
  reinterpret_cast<ushort4*>(lo)[i] = l;
}

// ---- K prep: split + retile into k-major MFMA-fragment order --------------
// K_t layout (per plane): [k0(8)][jg(128)][lane(64)][8 shorts]
//   lane lam <-> (row = jg*16 + (lam&15), col = k0*32 + (lam>>4)*8)
// A wave's (k0, j=0..15) B-frags are 16 KB CONTIGUOUS (1 KB per frag).
__global__ void k_prepk(const float* __restrict__ keys,
                        unsigned short* __restrict__ th,
                        unsigned short* __restrict__ tl) {
  int g = blockIdx.x * blockDim.x + threadIdx.x;  // 65536 chunks of 8 elems
  int k0 = g >> 13, rem = g & 8191;
  int jg = rem >> 6, lam = rem & 63;
  int row = jg * 16 + (lam & 15);
  int col = k0 * 32 + (lam >> 4) * 8;
  const float* s = keys + (size_t)row * 256 + col;
  float4 v0 = *reinterpret_cast<const float4*>(s);
  float4 v1 = *reinterpret_cast<const float4*>(s + 4);
  ushort4 h0, h1, l0, l1;
  h0.x = f2bf(v0.x); l0.x = f2bf(v0.x - bf2f(h0.x));
  h0.y = f2bf(v0.y); l0.y = f2bf(v0.y - bf2f(h0.y));
  h0.z = f2bf(v0.z); l0.z = f2bf(v0.z - bf2f(h0.z));
  h0.w = f2bf(v0.w); l0.w = f2bf(v0.w - bf2f(h0.w));
  h1.x = f2bf(v1.x); l1.x = f2bf(v1.x - bf2f(h1.x));
  h1.y = f2bf(v1.y); l1.y = f2bf(v1.y - bf2f(h1.y));
  h1.z = f2bf(v1.z); l1.z = f2bf(v1.z - bf2f(h1.z));
  h1.w = f2bf(v1.w); l1.w = f2bf(v1.w - bf2f(h1.w));
  reinterpret_cast<ushort4*>(th + (size_t)g * 8)[0] = h0;
  reinterpret_cast<ushort4*>(th + (size_t)g * 8)[1] = h1;
  reinterpret_cast<ushort4*>(tl + (size_t)g * 8)[0] = l0;
  reinterpret_cast<ushort4*>(tl + (size_t)g * 8)[1] = l1;
}

// ---------------- transpose + split Wq [1024,4096] -> WqT [4096,1024] ------
__global__ void k_twq(const float* __restrict__ W,
                      unsigned short* __restrict__ th,
                      unsigned short* __restrict__ tl) {
  __shared__ float t[64][65];
  int tx = threadIdx.x & 63, ty = threadIdx.x >> 6;
  int c0 = blockIdx.x * 64, r0 = blockIdx.y * 64;
#pragma unroll
  for (int i = 0; i < 64; i += 4)
    t[ty + i][tx] = W[(size_t)(r0 + ty + i) * 4096 + (c0 + tx)] * 0.25f;
  __syncthreads();
#pragma unroll
  for (int i = 0; i < 64; i += 4) {
    float v = t[tx][ty + i];
    unsigned short h = f2bf(v);
    unsigned short l = f2bf(v - bf2f(h));
    size_t o = (size_t)(c0 + ty + i) * 1024 + (r0 + tx);
    th[o] = h; tl[o] = l;
  }
}

// ------------------- GEMM1: q = x @ WqT', both [.,K] row-major -------------
__global__ __launch_bounds__(256) void k_gemm1(
    const unsigned short* __restrict__ Ah, const unsigned short* __restrict__ Al,
    const unsigned short* __restrict__ Bh, const unsigned short* __restrict__ Bl,
    unsigned short* __restrict__ Qh, unsigned short* __restrict__ Ql) {
  __shared__ unsigned short As[2][128][32];
  __shared__ unsigned short Bs[2][128][32];
  const int tid = threadIdx.x;
  const int w = tid >> 6, l = tid & 63;
  const int lr = l & 15, lg = l >> 4;
  const int m0 = blockIdx.y * 128, n0 = blockIdx.x * 128;
  const int wr = (w >> 1) * 64, wc = (w & 1) * 64;
  const int srow = tid >> 2;
  const int skel = (tid & 3) * 8;
  f32x4 acc[4][4] = {};

  const size_t gaBase = (size_t)(m0 + srow) * 1024 + skel;
  const size_t gbBase = (size_t)(n0 + srow) * 1024 + skel;
  char* lA0 = (char*)&As[0][0][0] + w * 1024;
  char* lA1 = (char*)&As[1][0][0] + w * 1024;
  char* lB0 = (char*)&Bs[0][0][0] + w * 1024;
  char* lB1 = (char*)&Bs[1][0][0] + w * 1024;

  for (int k0 = 0; k0 < 1024; k0 += 32) {
    gload16(Ah + gaBase + k0,             lA0);
    gload16(Ah + gaBase + 64 * 1024 + k0, lA0 + 4096);
    gload16(Al + gaBase + k0,             lA1);
    gload16(Al + gaBase + 64 * 1024 + k0, lA1 + 4096);
    gload16(Bh + gbBase + k0,             lB0);
    gload16(Bh + gbBase + 64 * 1024 + k0, lB0 + 4096);
    gload16(Bl + gbBase + k0,             lB1);
    gload16(Bl + gbBase + 64 * 1024 + k0, lB1 + 4096);
    __syncthreads();
    bf16x8 ah[4], am[4], bh[4], bm[4];
#pragma unroll
    for (int i = 0; i < 4; ++i) {
      ah[i] = *reinterpret_cast<const bf16x8*>(&As[0][wr + i * 16 + lr][lg * 8]);
      am[i] = *reinterpret_cast<const bf16x8*>(&As[1][wr + i * 16 + lr][lg * 8]);
      bh[i] = *reinterpret_cast<const bf16x8*>(&Bs[0][wc + i * 16 + lr][lg * 8]);
      bm[i] = *reinterpret_cast<const bf16x8*>(&Bs[1][wc + i * 16 + lr][lg * 8]);
    }
#pragma unroll
    for (int i = 0; i < 4; ++i)
#pragma unroll
      for (int j = 0; j < 4; ++j) {
        acc[i][j] = __builtin_amdgcn_mfma_f32_16x16x32_bf16(ah[i], bh[j], acc[i][j], 0, 0, 0);
        acc[i][j] = __builtin_amdgcn_mfma_f32_16x16x32_bf16(am[i], bh[j], acc[i][j], 0, 0, 0);
        acc[i][j] = __builtin_amdgcn_mfma_f32_16x16x32_bf16(ah[i], bm[j], acc[i][j], 0, 0, 0);
      }
    __syncthreads();
  }
#pragma unroll
  for (int i = 0; i < 4; ++i)
#pragma unroll
    for (int j = 0; j < 4; ++j)
#pragma unroll
      for (int r = 0; r < 4; ++r) {
        int row = m0 + wr + i * 16 + lg * 4 + r;
        int col = n0 + wc + j * 16 + lr;
        float v = acc[i][j][r];
        unsigned short hh = f2bf(v);
        unsigned short ll = f2bf(v - bf2f(hh));
        size_t o = (size_t)row * 4096 + col;
        Qh[o] = hh; Ql[o] = ll;
      }
}

// ---- fused GEMM2 + double softmax + head-mean (v5) -------------------------
#define MFMA_BF16(a, b, c) __builtin_amdgcn_mfma_f32_16x16x32_bf16(a, b, c, 0, 0, 0)

// byte offset of issue T (T = k0*16 + j) inside a wave's plane stream
#define C_OF(T) ((unsigned)((((T) >> 4) * 128 + ((T) & 15)) * 1024))

#define LOADB(SLOT, T)                                                        \
  B##SLOT = *reinterpret_cast<const bf16x8*>(kHb + (vbase + C_OF(T)));        \
  L##SLOT = *reinterpret_cast<const bf16x8*>(kLb + (vbase + C_OF(T)));

// one j-step: 6 MFMAs (prio-boosted) on slot, then reload slot for issue T
#define JST(J, SLOT, PF, T)                          \
  __builtin_amdgcn_s_setprio(1);                     \
  acc[0][J] = MFMA_BF16(ah0, B##SLOT, acc[0][J]);    \
  acc[1][J] = MFMA_BF16(ah1, B##SLOT, acc[1][J]);    \
  acc[0][J] = MFMA_BF16(am0, B##SLOT, acc[0][J]);    \
  acc[1][J] = MFMA_BF16(am1, B##SLOT, acc[1][J]);    \
  acc[0][J] = MFMA_BF16(ah0, L##SLOT, acc[0][J]);    \
  acc[1][J] = MFMA_BF16(ah1, L##SLOT, acc[1][J]);    \
  __builtin_amdgcn_s_setprio(0);                     \
  if (PF) { LOADB(SLOT, T) }

#define BODY_HEAD(K)                                                   \
  ah0 = *reinterpret_cast<const bf16x8*>(As + ((K)) * 512 + l8);       \
  ah1 = *reinterpret_cast<const bf16x8*>(As + (8 + (K)) * 512 + l8);   \
  am0 = *reinterpret_cast<const bf16x8*>(As + (16 + (K)) * 512 + l8);  \
  am1 = *reinterpret_cast<const bf16x8*>(As + (24 + (K)) * 512 + l8);

#define BODY(K)                        \
  BODY_HEAD(K)                         \
  JST(0,  0, 1, (K) * 16 + 4)          \
  JST(1,  1, 1, (K) * 16 + 5)          \
  JST(2,  2, 1, (K) * 16 + 6)          \
  JST(3,  3, 1, (K) * 16 + 7)          \
  JST(4,  0, 1, (K) * 16 + 8)          \
  JST(5,  1, 1, (K) * 16 + 9)          \
  JST(6,  2, 1, (K) * 16 + 10)         \
  JST(7,  3, 1, (K) * 16 + 11)         \
  JST(8,  0, 1, (K) * 16 + 12)         \
  JST(9,  1, 1, (K) * 16 + 13)         \
  JST(10, 2, 1, (K) * 16 + 14)         \
  JST(11, 3, 1, (K) * 16 + 15)         \
  JST(12, 0, 1, (K) * 16 + 16)         \
  JST(13, 1, 1, (K) * 16 + 17)         \
  JST(14, 2, 1, (K) * 16 + 18)         \
  JST(15, 3, 1, (K) * 16 + 19)

#define BODY7            \
  BODY_HEAD(7)           \
  JST(0,  0, 1, 116)     \
  JST(1,  1, 1, 117)     \
  JST(2,  2, 1, 118)     \
  JST(3,  3, 1, 119)     \
  JST(4,  0, 1, 120)     \
  JST(5,  1, 1, 121)     \
  JST(6,  2, 1, 122)     \
  JST(7,  3, 1, 123)     \
  JST(8,  0, 1, 124)     \
  JST(9,  1, 1, 125)     \
  JST(10, 2, 1, 126)     \
  JST(11, 3, 1, 127)     \
  JST(12, 0, 0, 0)       \
  JST(13, 1, 0, 0)       \
  JST(14, 2, 0, 0)       \
  JST(15, 3, 0, 0)

// block: 512 thr (8 waves), 32 q2-rows, full N=2048; wave w owns the
// staggered col-slice ((w + bid) & 7)*256. K loads: SGPR base (wave-uniform,
// readfirstlane) + 32-bit voffset, monotone 1KB stride within each body.
__global__ __launch_bounds__(512, 2) void k_attn(
    const unsigned short* __restrict__ Qh, const unsigned short* __restrict__ Ql,
    const unsigned short* __restrict__ KtH, const unsigned short* __restrict__ KtL,
    const float* __restrict__ values, const float* __restrict__ cur,
    float* __restrict__ out) {
  __shared__ unsigned short As[32 * 512];  // q frags, 32 KiB
  __shared__ float red[8][32];
  const int tid = threadIdx.x;
  const int w = tid >> 6, l = tid & 63;
  const int lr = l & 15, lg = l >> 4;
  const int r0 = blockIdx.x * 32;              // q2 row base
  const int cs = (int)((w + blockIdx.x) & 7);  // staggered col-slice
  const int n0 = cs * 256;
  const int l8 = l * 8;

  // ---- stage q rows (hi+lo) into frag-major LDS; wave w does slots w*4..+3
#pragma unroll
  for (int qq = 0; qq < 4; ++qq) {
    const int s = w * 4 + qq;
    const int plane = s >> 4, mf = (s >> 3) & 1, k0s = s & 7;
    const unsigned short* src = plane ? Ql : Qh;
    const size_t ga = (size_t)(r0 + mf * 16 + lr) * 256 + k0s * 32 + lg * 8;
    gload16(src + ga, (char*)As + s * 1024);
  }
  __syncthreads();

  // wave-uniform K slice base (SGPR) + per-lane 32-bit voffset
  const unsigned sliceB = (unsigned)__builtin_amdgcn_readfirstlane(cs * 16384);
  const char* kHb = (const char*)KtH + sliceB;
  const char* kLb = (const char*)KtL + sliceB;
  const unsigned vbase = (unsigned)(l * 16);

  f32x4 acc[2][16] = {};
  bf16x8 B0, B1, B2, B3, L0, L1, L2, L3;
  bf16x8 ah0, ah1, am0, am1;

  // prologue: 4 pairs in flight (issues 0..3)
  LOADB(0, 0) LOADB(1, 1) LOADB(2, 2) LOADB(3, 3)

  BODY(0) BODY(1) BODY(2) BODY(3) BODY(4) BODY(5) BODY(6) BODY7

  // logits = acc + values[n]
#pragma unroll
  for (int j = 0; j < 16; ++j) {
    float vv = values[n0 + j * 16 + lr];
#pragma unroll
    for (int mf = 0; mf < 2; ++mf)
#pragma unroll
      for (int r = 0; r < 4; ++r) acc[mf][j][r] += vv;
  }

  const int rb = lg * 4;
  // ---------------- first softmax: row max ----------------
  float M1[2][4];
#pragma unroll
  for (int mf = 0; mf < 2; ++mf)
#pragma unroll
    for (int r = 0; r < 4; ++r) {
      float m = acc[mf][0][r];
#pragma unroll
      for (int j = 1; j < 16; ++j) m = fmaxf(m, acc[mf][j][r]);
      m = fmaxf(m, __shfl_xor(m, 1));
      m = fmaxf(m, __shfl_xor(m, 2));
      m = fmaxf(m, __shfl_xor(m, 4));
      m = fmaxf(m, __shfl_xor(m, 8));
      M1[mf][r] = m;
    }
  if (lr == 0) {
#pragma unroll
    for (int mf = 0; mf < 2; ++mf)
#pragma unroll
      for (int r = 0; r < 4; ++r) red[w][mf * 16 + rb + r] = M1[mf][r];
  }
  __syncthreads();
#pragma unroll
  for (int mf = 0; mf < 2; ++mf)
#pragma unroll
    for (int r = 0; r < 4; ++r) {
      float m = red[0][mf * 16 + rb + r];
#pragma unroll
      for (int w2 = 1; w2 < 8; ++w2) m = fmaxf(m, red[w2][mf * 16 + rb + r]);
      M1[mf][r] = m;
    }
  __syncthreads();
  // ---------------- e1 = exp(l - M1), Z1 ----------------
  float Z1[2][4];
#pragma unroll
  for (int mf = 0; mf < 2; ++mf)
#pragma unroll
    for (int r = 0; r < 4; ++r) {
      float z = 0.f;
#pragma unroll
      for (int j = 0; j < 16; ++j) {
        float e = __expf(acc[mf][j][r] - M1[mf][r]);
        acc[mf][j][r] = e;
        z += e;
      }
      z += __shfl_xor(z, 1); z += __shfl_xor(z, 2);
      z += __shfl_xor(z, 4); z += __shfl_xor(z, 8);
      Z1[mf][r] = z;
    }
  if (lr == 0) {
#pragma unroll
    for (int mf = 0; mf < 2; ++mf)
#pragma unroll
      for (int r = 0; r < 4; ++r) red[w][mf * 16 + rb + r] = Z1[mf][r];
  }
  __syncthreads();
#pragma unroll
  for (int mf = 0; mf < 2; ++mf)
#pragma unroll
    for (int r = 0; r < 4; ++r) {
      float z = 0.f;
#pragma unroll
      for (int w2 = 0; w2 < 8; ++w2) z += red[w2][mf * 16 + rb + r];
      Z1[mf][r] = z;
    }
  __syncthreads();
  // ---------------- second softmax (max(logits2) = c/Z1 exactly) -----------
  const float c0 = __expf(cur[(r0 >> 4) + 0]);
  const float c1 = __expf(cur[(r0 >> 4) + 1]);
  float Z2[2][4];
#pragma unroll
  for (int mf = 0; mf < 2; ++mf)
#pragma unroll
    for (int r = 0; r < 4; ++r) {
      float s2 = (mf ? c1 : c0) / Z1[mf][r];
      float z = 0.f;
#pragma unroll
      for (int j = 0; j < 16; ++j) {
        float o = __expf(s2 * (acc[mf][j][r] - 1.0f));
        acc[mf][j][r] = o;
        z += o;
      }
      z += __shfl_xor(z, 1); z += __shfl_xor(z, 2);
      z += __shfl_xor(z, 4); z += __shfl_xor(z, 8);
      Z2[mf][r] = z;
    }
  if (lr == 0) {
#pragma unroll
    for (int mf = 0; mf < 2; ++mf)
#pragma unroll
      for (int r = 0; r < 4; ++r) red[w][mf * 16 + rb + r] = Z2[mf][r];
  }
  __syncthreads();
#pragma unroll
  for (int mf = 0; mf < 2; ++mf)
#pragma unroll
    for (int r = 0; r < 4; ++r) {
      float z = 0.f;
#pragma unroll
      for (int w2 = 0; w2 < 8; ++w2) z += red[w2][mf * 16 + rb + r];
      Z2[mf][r] = z;
    }
  // ---------------- head-mean + write ----------------
  float rz[2][4];
#pragma unroll
  for (int mf = 0; mf < 2; ++mf)
#pragma unroll
    for (int r = 0; r < 4; ++r) rz[mf][r] = 1.0f / (16.0f * Z2[mf][r]);
#pragma unroll
  for (int mf = 0; mf < 2; ++mf)
#pragma unroll
    for (int j = 0; j < 16; ++j) {
      float s = acc[mf][j][0] * rz[mf][0] + acc[mf][j][1] * rz[mf][1] +
                acc[mf][j][2] * rz[mf][2] + acc[mf][j][3] * rz[mf][3];
      s += __shfl_xor(s, 16);
      s += __shfl_xor(s, 32);
      if (l < 16)
        out[(size_t)((r0 >> 4) + mf) * 2048 + n0 + j * 16 + l] = s;
    }
}

// ---------------------------------------------------------------------------
extern "C" void kernel_launch(void* const* d_in, const int* in_sizes, int n_in,
                              void* d_out, int out_size, void* d_ws, size_t ws_size,
                              hipStream_t stream) {
  const float* x    = (const float*)d_in[0];
  const float* cur  = (const float*)d_in[1];
  const float* Wq   = (const float*)d_in[2];
  const float* keys = (const float*)d_in[3];
  const float* vals = (const float*)d_in[4];
  float* out = (float*)d_out;

  char* ws = (char*)d_ws;
  unsigned short* x_hi = (unsigned short*)ws;  ws += (size_t)4096 * 1024 * 2;
  unsigned short* x_lo = (unsigned short*)ws;  ws += (size_t)4096 * 1024 * 2;
  unsigned short* w_hi = (unsigned short*)ws;  ws += (size_t)4096 * 1024 * 2;
  unsigned short* w_lo = (unsigned short*)ws;  ws += (size_t)4096 * 1024 * 2;
  unsigned short* k_hi = (unsigned short*)ws;  ws += (size_t)2048 * 256 * 2;
  unsigned short* k_lo = (unsigned short*)ws;  ws += (size_t)2048 * 256 * 2;
  unsigned short* q_hi = (unsigned short*)ws;  ws += (size_t)4096 * 4096 * 2;
  unsigned short* q_lo = (unsigned short*)ws;

  k_split<<<4096, 256, 0, stream>>>(x, x_hi, x_lo, 4096 * 1024 / 4);
  k_prepk<<<256, 256, 0, stream>>>(keys, k_hi, k_lo);
  k_twq<<<dim3(64, 16), 256, 0, stream>>>(Wq, w_hi, w_lo);
  k_gemm1<<<dim3(32, 32), 256, 0, stream>>>(x_hi, x_lo, w_hi, w_lo, q_hi, q_lo);
  k_attn<<<2048, 512, 0, stream>>>(q_hi, q_lo, k_hi, k_lo, vals, cur, out);
}